// Round 1
// baseline (137.073 us; speedup 1.0000x reference)
//
#include <hip/hip_runtime.h>

#define NB 32
#define NS 2048
// softmax scale 1/sqrt(d_k)=0.5 folded with the 1/4 range reduction for the
// packed-FMA exp:  u = (q.k)*0.5*0.25  ->  P = (T6(u)^2)^2 ~= e^{0.5*q.k}
#define QSCALE 0.125f

typedef float v2f __attribute__((ext_vector_type(2)));
typedef float v4f __attribute__((ext_vector_type(4)));

// Packed f32 math via native vector ops -> LLVM selects v_pk_{mul,fma,add}_f32
// on gfx90a+ with correct op_sel/op_sel_hi.
__device__ __forceinline__ v2f pkfma(v2f a, v2f b, v2f c) {
  return __builtin_elementwise_fma(a, b, c);
}
__device__ __forceinline__ v2f make2(float a) { return (v2f){a, a}; }

// e^{4u} for u in [-0.5,0.5], entirely on the full-rate packed-f32 pipe.
// v_exp_f32 is quarter-rate (16 cyc/wave64) on gfx950 and was the measured
// bottleneck (4 exps/j = 64 of ~100 busy cycles). Degree-6 Taylor of e^u
// (exact 1/k! coeffs, |rel err| ~ 4e-6) + two squarings (~1.7e-5 on P):
// 6 v_pk_fma + 2 v_pk_mul = 16 cycles for BOTH heads vs 32 for 2x v_exp_f32.
__device__ __forceinline__ v2f pexp4(v2f u) {
  v2f p = pkfma(make2(1.38888893e-3f), u, make2(8.33333377e-3f));  // 1/720,1/120
  p = pkfma(p, u, make2(4.16666679e-2f));  // 1/24
  p = pkfma(p, u, make2(0.166666672f));    // 1/6
  p = pkfma(p, u, make2(0.5f));
  p = pkfma(p, u, make2(1.0f));
  p = pkfma(p, u, make2(1.0f));
  p = p * p;
  return p * p;
}

// ---------------------------------------------------------------------------
// Fully-fused attention: BLOCK-LOCAL split-K, no workspace, no 2nd kernel.
//   - block = 256 threads = 4 waves; block owns 128 q-rows (QPT=2 per lane).
//   - wave w processes k-quarter w (512 of 2048 k-rows).
//   - k staged in 2 chunks of 1024 rows (256 per quarter) = 32 KB LDS
//     (5 barriers total vs 9 with 4x512), head-interleaved
//     (k0,k4,k1,k5)(k2,k6,k3,k7) so both heads ride lo/hi halves of v_pk_*.
//     Wave LDS reads are single-address broadcasts (conflict-free).
//   - chunk 1's global loads are PREFETCHED into registers before chunk 0's
//     compute loop, so the mid-kernel restage is cos+ds_write only (no
//     exposed HBM/L2 latency between barriers).
//   - scores bounded in [-2,2] (h = cos(..)) -> single-pass exp, no max;
//     exp computed as a packed-FMA polynomial (see pexp4), NOT v_exp_f32,
//     keeping the whole inner loop on the full-rate packed pipe.
//   - merge: waves 1-3 dump 20 partial floats via LDS (stride 21, gcd(21,32)
//     =1 -> conflict-free), wave 0 sums, normalizes, projects W_out, stores.
// ---------------------------------------------------------------------------
__global__ __launch_bounds__(256, 2) void attn_fused_kernel(
    const float* __restrict__ x, const float* __restrict__ theta,
    const float* __restrict__ Wout, float* __restrict__ outp) {
  // 1024 rows x 8 floats = 32 KB; reused as the merge buffer at the end.
  __shared__ __align__(16) float kv[1024 * 8];

  const int b = blockIdx.y;
  const int t = threadIdx.x;
  const int w = t >> 6;    // wave index == k-quarter
  const int lane = t & 63;
  const int qbase = blockIdx.x * 128;

  float th[8];
#pragma unroll
  for (int e = 0; e < 8; ++e) th[e] = theta[e];

  // ---- stage chunk 0 (1024 rows; 256 per quarter) ----
  // thread handles rows l = t + 256*i; qtr = l>>8, rr = l&255
#pragma unroll
  for (int i = 0; i < 4; ++i) {
    const int l = t + 256 * i;
    const int qtr = l >> 8;
    const int rr = l & 255;
    const int gk = qtr * 512 + rr;  // chunk 0
    const float4* xr = (const float4*)(x + ((size_t)b * NS + gk) * 8);
    float4 lo = xr[0], hi = xr[1];
    lo.x = __cosf(lo.x + th[0]);
    lo.y = __cosf(lo.y + th[1]);
    lo.z = __cosf(lo.z + th[2]);
    lo.w = __cosf(lo.w + th[3]);
    hi.x = __cosf(hi.x + th[4]);
    hi.y = __cosf(hi.y + th[5]);
    hi.z = __cosf(hi.z + th[6]);
    hi.w = __cosf(hi.w + th[7]);
    ((float4*)kv)[2 * l] = make_float4(lo.x, hi.x, lo.y, hi.y);
    ((float4*)kv)[2 * l + 1] = make_float4(lo.z, hi.z, lo.w, hi.w);
  }

  // ---- prefetch chunk 1's raw x rows into registers (loads in flight
  //      across chunk 0's entire compute loop) ----
  float4 pf[4][2];
#pragma unroll
  for (int i = 0; i < 4; ++i) {
    const int l = t + 256 * i;
    const int qtr = l >> 8;
    const int rr = l & 255;
    const int gk = qtr * 512 + 256 + rr;  // chunk 1
    const float4* xr = (const float4*)(x + ((size_t)b * NS + gk) * 8);
    pf[i][0] = xr[0];
    pf[i][1] = xr[1];
  }

  // This lane's 2 query rows as head-interleaved pairs, pre-scaled.
  v2f qp[2][4];
#pragma unroll
  for (int g = 0; g < 2; ++g) {
    const float4* xq =
        (const float4*)(x + ((size_t)b * NS + qbase + 64 * g + lane) * 8);
    float4 lo = xq[0], hi = xq[1];
    qp[g][0] = (v2f){__cosf(lo.x + th[0]) * QSCALE, __cosf(hi.x + th[4]) * QSCALE};
    qp[g][1] = (v2f){__cosf(lo.y + th[1]) * QSCALE, __cosf(hi.y + th[5]) * QSCALE};
    qp[g][2] = (v2f){__cosf(lo.z + th[2]) * QSCALE, __cosf(hi.z + th[6]) * QSCALE};
    qp[g][3] = (v2f){__cosf(lo.w + th[3]) * QSCALE, __cosf(hi.w + th[7]) * QSCALE};
  }

  v2f acc[2][4];  // acc[g][i] = (sum p0*k_i, sum p1*k_{4+i})
  v2f den[2];     // (sum p0, sum p1)
#pragma unroll
  for (int g = 0; g < 2; ++g) {
    acc[g][0] = (v2f){0.f, 0.f};
    acc[g][1] = (v2f){0.f, 0.f};
    acc[g][2] = (v2f){0.f, 0.f};
    acc[g][3] = (v2f){0.f, 0.f};
    den[g] = (v2f){0.f, 0.f};
  }

  __syncthreads();  // (1) chunk 0 staged

  // ---- compute chunk 0: wave w reads LDS rows [w*256, w*256+256) ----
  {
    const v4f* kp = (const v4f*)kv + (size_t)w * 512;
#pragma unroll 4
    for (int j = 0; j < 256; ++j) {
      v4f A = kp[2 * j];
      v4f Bv = kp[2 * j + 1];
      v2f kk0 = A.xy, kk1 = A.zw, kk2 = Bv.xy, kk3 = Bv.zw;
#pragma unroll
      for (int g = 0; g < 2; ++g) {
        v2f s = qp[g][0] * kk0;
        s = pkfma(qp[g][1], kk1, s);
        s = pkfma(qp[g][2], kk2, s);
        s = pkfma(qp[g][3], kk3, s);
        v2f P = pexp4(s);
        acc[g][0] = pkfma(P, kk0, acc[g][0]);
        acc[g][1] = pkfma(P, kk1, acc[g][1]);
        acc[g][2] = pkfma(P, kk2, acc[g][2]);
        acc[g][3] = pkfma(P, kk3, acc[g][3]);
        den[g] = den[g] + P;
      }
    }
  }

  __syncthreads();  // (2) chunk 0 fully consumed

  // ---- restage chunk 1 from prefetched registers (no memory latency) ----
#pragma unroll
  for (int i = 0; i < 4; ++i) {
    const int l = t + 256 * i;
    float4 lo = pf[i][0], hi = pf[i][1];
    lo.x = __cosf(lo.x + th[0]);
    lo.y = __cosf(lo.y + th[1]);
    lo.z = __cosf(lo.z + th[2]);
    lo.w = __cosf(lo.w + th[3]);
    hi.x = __cosf(hi.x + th[4]);
    hi.y = __cosf(hi.y + th[5]);
    hi.z = __cosf(hi.z + th[6]);
    hi.w = __cosf(hi.w + th[7]);
    ((float4*)kv)[2 * l] = make_float4(lo.x, hi.x, lo.y, hi.y);
    ((float4*)kv)[2 * l + 1] = make_float4(lo.z, hi.z, lo.w, hi.w);
  }

  __syncthreads();  // (3) chunk 1 staged

  // ---- compute chunk 1 ----
  {
    const v4f* kp = (const v4f*)kv + (size_t)w * 512;
#pragma unroll 4
    for (int j = 0; j < 256; ++j) {
      v4f A = kp[2 * j];
      v4f Bv = kp[2 * j + 1];
      v2f kk0 = A.xy, kk1 = A.zw, kk2 = Bv.xy, kk3 = Bv.zw;
#pragma unroll
      for (int g = 0; g < 2; ++g) {
        v2f s = qp[g][0] * kk0;
        s = pkfma(qp[g][1], kk1, s);
        s = pkfma(qp[g][2], kk2, s);
        s = pkfma(qp[g][3], kk3, s);
        v2f P = pexp4(s);
        acc[g][0] = pkfma(P, kk0, acc[g][0]);
        acc[g][1] = pkfma(P, kk1, acc[g][1]);
        acc[g][2] = pkfma(P, kk2, acc[g][2]);
        acc[g][3] = pkfma(P, kk3, acc[g][3]);
        den[g] = den[g] + P;
      }
    }
  }

  // ---- block-local split-K merge through LDS ----
  __syncthreads();  // (4) all waves done reading kv as k-tiles
  if (w > 0) {
    // stride 21 floats per lane: gcd(21,32)=1 -> no systematic bank conflict
    float* mb = kv + ((size_t)(w - 1) * 64 + lane) * 21;
#pragma unroll
    for (int g = 0; g < 2; ++g) {
      mb[10 * g + 0] = acc[g][0].x;
      mb[10 * g + 1] = acc[g][0].y;
      mb[10 * g + 2] = acc[g][1].x;
      mb[10 * g + 3] = acc[g][1].y;
      mb[10 * g + 4] = acc[g][2].x;
      mb[10 * g + 5] = acc[g][2].y;
      mb[10 * g + 6] = acc[g][3].x;
      mb[10 * g + 7] = acc[g][3].y;
      mb[10 * g + 8] = den[g].x;
      mb[10 * g + 9] = den[g].y;
    }
  }
  __syncthreads();  // (5)
  if (w == 0) {
#pragma unroll
    for (int m = 0; m < 3; ++m) {
      const float* mb = kv + ((size_t)m * 64 + lane) * 21;
#pragma unroll
      for (int g = 0; g < 2; ++g) {
        acc[g][0].x += mb[10 * g + 0];
        acc[g][0].y += mb[10 * g + 1];
        acc[g][1].x += mb[10 * g + 2];
        acc[g][1].y += mb[10 * g + 3];
        acc[g][2].x += mb[10 * g + 4];
        acc[g][2].y += mb[10 * g + 5];
        acc[g][3].x += mb[10 * g + 6];
        acc[g][3].y += mb[10 * g + 7];
        den[g].x += mb[10 * g + 8];
        den[g].y += mb[10 * g + 9];
      }
    }
    // normalize + project (out = m @ W_out^T) + store
#pragma unroll
    for (int g = 0; g < 2; ++g) {
      const int q = qbase + 64 * g + lane;
      const float i0 = 1.0f / den[g].x, i1 = 1.0f / den[g].y;
      float m8[8] = {acc[g][0].x * i0, acc[g][1].x * i0, acc[g][2].x * i0,
                     acc[g][3].x * i0, acc[g][0].y * i1, acc[g][1].y * i1,
                     acc[g][2].y * i1, acc[g][3].y * i1};
      float o[8];
#pragma unroll
      for (int e = 0; e < 8; ++e) {
        float s = 0.f;
#pragma unroll
        for (int f = 0; f < 8; ++f) s += m8[f] * Wout[e * 8 + f];
        o[e] = s;
      }
      float4* op = (float4*)(outp + ((size_t)b * NS + q) * 8);
      op[0] = make_float4(o[0], o[1], o[2], o[3]);
      op[1] = make_float4(o[4], o[5], o[6], o[7]);
    }
  }
}

extern "C" void kernel_launch(void* const* d_in, const int* in_sizes, int n_in,
                              void* d_out, int out_size, void* d_ws,
                              size_t ws_size, hipStream_t stream) {
  const float* x = (const float*)d_in[0];      // [32, 2048, 8]
  const float* theta = (const float*)d_in[1];  // [8]
  const float* W = (const float*)d_in[2];      // [8, 8]
  float* out = (float*)d_out;                  // [32, 2048, 8]
  (void)d_ws;
  (void)ws_size;

  // 512 blocks (16 q-chunks x 32 batches) = 2 blocks/CU (32 KB LDS each),
  // 8 waves/CU.
  attn_fused_kernel<<<dim3(NS / 128, NB), 256, 0, stream>>>(x, theta, W, out);
}

// Round 2
// 115.695 us; speedup vs baseline: 1.1848x; 1.1848x over previous
//
#include <hip/hip_runtime.h>

#define NB 32
#define NS 2048
// softmax scale 1/sqrt(d_k)=0.5 folded with log2(e) so we can use v_exp_f32 (2^x)
#define QSCALE 0.72134752044448170367f

typedef float v2f __attribute__((ext_vector_type(2)));
typedef float v4f __attribute__((ext_vector_type(4)));

// Packed f32 math via native vector ops -> LLVM selects v_pk_{mul,fma,add}_f32.
// NOTE (R1 post-mortem): v_pk_* f32 is 4 cyc/wave64 (32 FMA-lanes/cyc/SIMD) --
// packing halves instruction count, NOT FLOP rate. v_exp_f32 ~8 cyc/wave64 on
// the separate trans pipe; keeping exp on trans is cheaper than any FMA-pipe
// polynomial (R1 regression: +32 cyc/j).
__device__ __forceinline__ v2f pkfma(v2f a, v2f b, v2f c) {
  return __builtin_elementwise_fma(a, b, c);
}

// ---------------------------------------------------------------------------
// Fully-fused attention: BLOCK-LOCAL split-K, no workspace, no 2nd kernel.
//   - block = 512 threads = 8 waves; block owns 128 q-rows (QPT=2 per lane).
//     (R2: was 4 waves -- 8 waves doubles occupancy to 4 waves/SIMD so the
//      trans-pipe exp and LDS/loop overhead hide under other waves' FMA issue.)
//   - wave w processes k-eighth w (256 of 2048 k-rows).
//   - k staged in 2 chunks of 1024 rows (128 per eighth) = 32 KB LDS
//     (5 barriers total), head-interleaved (k0,k4,k1,k5)(k2,k6,k3,k7) so both
//     heads ride lo/hi halves of v_pk_*. Wave LDS reads are single-address
//     broadcasts (conflict-free).
//   - chunk 1's global loads are PREFETCHED into registers before chunk 0's
//     compute loop, so the mid-kernel restage is cos+ds_write only.
//   - scores bounded in [-2,2] (h = cos(..)) -> single-pass exp, no max.
//   - merge: waves 1-7 dump 20 partial floats via LDS (stride 21, gcd(21,32)
//     =1 -> conflict-free), wave 0 sums, normalizes, projects W_out, stores.
//     Merge region needs 7*64*21 = 9408 floats -> kv sized 9408 (36.75 KB).
// ---------------------------------------------------------------------------
__global__ __launch_bounds__(512, 4) void attn_fused_kernel(
    const float* __restrict__ x, const float* __restrict__ theta,
    const float* __restrict__ Wout, float* __restrict__ outp) {
  // first 8192 floats: 1024 k-rows x 8; full 9408 reused as merge buffer.
  __shared__ __align__(16) float kv[9408];

  const int b = blockIdx.y;
  const int t = threadIdx.x;
  const int w = t >> 6;    // wave index == k-eighth
  const int lane = t & 63;
  const int qbase = blockIdx.x * 128;

  float th[8];
#pragma unroll
  for (int e = 0; e < 8; ++e) th[e] = theta[e];

  // ---- stage chunk 0 (1024 rows; first 128 rows of each eighth) ----
  // LDS slot l = t + 512*i; eighth e = l>>7, row-in-chunk rc = l&127
#pragma unroll
  for (int i = 0; i < 2; ++i) {
    const int l = t + 512 * i;
    const int e8 = l >> 7;
    const int rc = l & 127;
    const int gk = e8 * 256 + rc;  // chunk 0
    const float4* xr = (const float4*)(x + ((size_t)b * NS + gk) * 8);
    float4 lo = xr[0], hi = xr[1];
    lo.x = __cosf(lo.x + th[0]);
    lo.y = __cosf(lo.y + th[1]);
    lo.z = __cosf(lo.z + th[2]);
    lo.w = __cosf(lo.w + th[3]);
    hi.x = __cosf(hi.x + th[4]);
    hi.y = __cosf(hi.y + th[5]);
    hi.z = __cosf(hi.z + th[6]);
    hi.w = __cosf(hi.w + th[7]);
    ((float4*)kv)[2 * l] = make_float4(lo.x, hi.x, lo.y, hi.y);
    ((float4*)kv)[2 * l + 1] = make_float4(lo.z, hi.z, lo.w, hi.w);
  }

  // ---- prefetch chunk 1's raw x rows into registers (loads in flight
  //      across chunk 0's entire compute loop) ----
  float4 pf[2][2];
#pragma unroll
  for (int i = 0; i < 2; ++i) {
    const int l = t + 512 * i;
    const int e8 = l >> 7;
    const int rc = l & 127;
    const int gk = e8 * 256 + 128 + rc;  // chunk 1
    const float4* xr = (const float4*)(x + ((size_t)b * NS + gk) * 8);
    pf[i][0] = xr[0];
    pf[i][1] = xr[1];
  }

  // This lane's 2 query rows as head-interleaved pairs, pre-scaled.
  v2f qp[2][4];
#pragma unroll
  for (int g = 0; g < 2; ++g) {
    const float4* xq =
        (const float4*)(x + ((size_t)b * NS + qbase + 64 * g + lane) * 8);
    float4 lo = xq[0], hi = xq[1];
    qp[g][0] = (v2f){__cosf(lo.x + th[0]) * QSCALE, __cosf(hi.x + th[4]) * QSCALE};
    qp[g][1] = (v2f){__cosf(lo.y + th[1]) * QSCALE, __cosf(hi.y + th[5]) * QSCALE};
    qp[g][2] = (v2f){__cosf(lo.z + th[2]) * QSCALE, __cosf(hi.z + th[6]) * QSCALE};
    qp[g][3] = (v2f){__cosf(lo.w + th[3]) * QSCALE, __cosf(hi.w + th[7]) * QSCALE};
  }

  v2f acc[2][4];  // acc[g][i] = (sum p0*k_i, sum p1*k_{4+i})
  v2f den[2];     // (sum p0, sum p1)
#pragma unroll
  for (int g = 0; g < 2; ++g) {
    acc[g][0] = (v2f){0.f, 0.f};
    acc[g][1] = (v2f){0.f, 0.f};
    acc[g][2] = (v2f){0.f, 0.f};
    acc[g][3] = (v2f){0.f, 0.f};
    den[g] = (v2f){0.f, 0.f};
  }

  __syncthreads();  // (1) chunk 0 staged

  // ---- compute chunk 0: wave w reads LDS rows [w*128, w*128+128) ----
  {
    const v4f* kp = (const v4f*)kv + (size_t)w * 256;
#pragma unroll 4
    for (int j = 0; j < 128; ++j) {
      v4f A = kp[2 * j];
      v4f Bv = kp[2 * j + 1];
      v2f kk0 = A.xy, kk1 = A.zw, kk2 = Bv.xy, kk3 = Bv.zw;
#pragma unroll
      for (int g = 0; g < 2; ++g) {
        v2f s = qp[g][0] * kk0;
        s = pkfma(qp[g][1], kk1, s);
        s = pkfma(qp[g][2], kk2, s);
        s = pkfma(qp[g][3], kk3, s);
        v2f P;
        P.x = __builtin_amdgcn_exp2f(s.x);
        P.y = __builtin_amdgcn_exp2f(s.y);
        acc[g][0] = pkfma(P, kk0, acc[g][0]);
        acc[g][1] = pkfma(P, kk1, acc[g][1]);
        acc[g][2] = pkfma(P, kk2, acc[g][2]);
        acc[g][3] = pkfma(P, kk3, acc[g][3]);
        den[g] = den[g] + P;
      }
    }
  }

  __syncthreads();  // (2) chunk 0 fully consumed

  // ---- restage chunk 1 from prefetched registers (no memory latency) ----
#pragma unroll
  for (int i = 0; i < 2; ++i) {
    const int l = t + 512 * i;
    float4 lo = pf[i][0], hi = pf[i][1];
    lo.x = __cosf(lo.x + th[0]);
    lo.y = __cosf(lo.y + th[1]);
    lo.z = __cosf(lo.z + th[2]);
    lo.w = __cosf(lo.w + th[3]);
    hi.x = __cosf(hi.x + th[4]);
    hi.y = __cosf(hi.y + th[5]);
    hi.z = __cosf(hi.z + th[6]);
    hi.w = __cosf(hi.w + th[7]);
    ((float4*)kv)[2 * l] = make_float4(lo.x, hi.x, lo.y, hi.y);
    ((float4*)kv)[2 * l + 1] = make_float4(lo.z, hi.z, lo.w, hi.w);
  }

  __syncthreads();  // (3) chunk 1 staged

  // ---- compute chunk 1 ----
  {
    const v4f* kp = (const v4f*)kv + (size_t)w * 256;
#pragma unroll 4
    for (int j = 0; j < 128; ++j) {
      v4f A = kp[2 * j];
      v4f Bv = kp[2 * j + 1];
      v2f kk0 = A.xy, kk1 = A.zw, kk2 = Bv.xy, kk3 = Bv.zw;
#pragma unroll
      for (int g = 0; g < 2; ++g) {
        v2f s = qp[g][0] * kk0;
        s = pkfma(qp[g][1], kk1, s);
        s = pkfma(qp[g][2], kk2, s);
        s = pkfma(qp[g][3], kk3, s);
        v2f P;
        P.x = __builtin_amdgcn_exp2f(s.x);
        P.y = __builtin_amdgcn_exp2f(s.y);
        acc[g][0] = pkfma(P, kk0, acc[g][0]);
        acc[g][1] = pkfma(P, kk1, acc[g][1]);
        acc[g][2] = pkfma(P, kk2, acc[g][2]);
        acc[g][3] = pkfma(P, kk3, acc[g][3]);
        den[g] = den[g] + P;
      }
    }
  }

  // ---- block-local split-K merge through LDS ----
  __syncthreads();  // (4) all waves done reading kv as k-tiles
  if (w > 0) {
    // stride 21 floats per lane: gcd(21,32)=1 -> no systematic bank conflict
    float* mb = kv + ((size_t)(w - 1) * 64 + lane) * 21;
#pragma unroll
    for (int g = 0; g < 2; ++g) {
      mb[10 * g + 0] = acc[g][0].x;
      mb[10 * g + 1] = acc[g][0].y;
      mb[10 * g + 2] = acc[g][1].x;
      mb[10 * g + 3] = acc[g][1].y;
      mb[10 * g + 4] = acc[g][2].x;
      mb[10 * g + 5] = acc[g][2].y;
      mb[10 * g + 6] = acc[g][3].x;
      mb[10 * g + 7] = acc[g][3].y;
      mb[10 * g + 8] = den[g].x;
      mb[10 * g + 9] = den[g].y;
    }
  }
  __syncthreads();  // (5)
  if (w == 0) {
#pragma unroll
    for (int m = 0; m < 7; ++m) {
      const float* mb = kv + ((size_t)m * 64 + lane) * 21;
#pragma unroll
      for (int g = 0; g < 2; ++g) {
        acc[g][0].x += mb[10 * g + 0];
        acc[g][0].y += mb[10 * g + 1];
        acc[g][1].x += mb[10 * g + 2];
        acc[g][1].y += mb[10 * g + 3];
        acc[g][2].x += mb[10 * g + 4];
        acc[g][2].y += mb[10 * g + 5];
        acc[g][3].x += mb[10 * g + 6];
        acc[g][3].y += mb[10 * g + 7];
        den[g].x += mb[10 * g + 8];
        den[g].y += mb[10 * g + 9];
      }
    }
    // normalize + project (out = m @ W_out^T) + store
#pragma unroll
    for (int g = 0; g < 2; ++g) {
      const int q = qbase + 64 * g + lane;
      const float i0 = 1.0f / den[g].x, i1 = 1.0f / den[g].y;
      float m8[8] = {acc[g][0].x * i0, acc[g][1].x * i0, acc[g][2].x * i0,
                     acc[g][3].x * i0, acc[g][0].y * i1, acc[g][1].y * i1,
                     acc[g][2].y * i1, acc[g][3].y * i1};
      float o[8];
#pragma unroll
      for (int e = 0; e < 8; ++e) {
        float s = 0.f;
#pragma unroll
        for (int f = 0; f < 8; ++f) s += m8[f] * Wout[e * 8 + f];
        o[e] = s;
      }
      float4* op = (float4*)(outp + ((size_t)b * NS + q) * 8);
      op[0] = make_float4(o[0], o[1], o[2], o[3]);
      op[1] = make_float4(o[4], o[5], o[6], o[7]);
    }
  }
}

extern "C" void kernel_launch(void* const* d_in, const int* in_sizes, int n_in,
                              void* d_out, int out_size, void* d_ws,
                              size_t ws_size, hipStream_t stream) {
  const float* x = (const float*)d_in[0];      // [32, 2048, 8]
  const float* theta = (const float*)d_in[1];  // [8]
  const float* W = (const float*)d_in[2];      // [8, 8]
  float* out = (float*)d_out;                  // [32, 2048, 8]
  (void)d_ws;
  (void)ws_size;

  // 512 blocks (16 q-chunks x 32 batches) of 8 waves = 2 blocks/CU,
  // 16 waves/CU = 4 waves/SIMD (36.75 KB LDS each, 73.5 KB/CU).
  attn_fused_kernel<<<dim3(NS / 128, NB), 512, 0, stream>>>(x, theta, W, out);
}

// Round 4
// 112.258 us; speedup vs baseline: 1.2211x; 1.0306x over previous
//
#include <hip/hip_runtime.h>

#define NB 32
#define NS 2048
// (1/sqrt(d_k)) * log2(e) folded into q so scores feed v_exp_f32 (2^x) directly
#define QS 0.72134752044448170367f

typedef _Float16 f16;
typedef _Float16 h2 __attribute__((ext_vector_type(2)));
typedef _Float16 h8 __attribute__((ext_vector_type(8)));
typedef float f32x4 __attribute__((ext_vector_type(4)));

__device__ __forceinline__ h2 cvt_pk_f16(float a, float b) {
  return __builtin_bit_cast(h2, __builtin_amdgcn_cvt_pkrtz(a, b));
}

// LDS geometry (units: halves/f16):
//   main      : [1024][8]  f16 k-rows (16 B/row)            -> 8192 halves
//   transposed: [10][1032] f16, row d = dim (0-7), 8 = ones, 9 = zeros
//               stride 1032 halves (2064 B) to spread banks  -> 10320 halves
#define TR_STRIDE 1032
#define TR_BASE 8192
#define LDS_HALVES (8192 + 10 * 1032)

// ---------------------------------------------------------------------------
// MFMA-based fused attention (R3 restructure).
//   - block = 512 thr = 8 waves; block owns 128 q (wave w owns q-tile of 16).
//   - wave walks all 2048 k in 64 steps of 32 (2 LDS chunks of 1024 rows).
//   - per step: lanes compute P[k][q] with v_dot2_f32_f16 + v_exp_f32,
//     already laid out as the MFMA B-fragment (lane = q-col lane&15,
//     lane-group g owns k-slots 8*((r+g)&3)+2g+p -- bank-conflict-free and
//     IDENTICAL formula for A + B builds, so the true HW k-permutation
//     cancels in the MFMA k-sum).
//   - A-fragment = h^T (4 dims of this head) + ones-row (m=4) + zero rows,
//     read as contiguous f16 pairs from the transposed LDS copy. One
//     v_mfma_f32_16x16x32_f16 per head per step accumulates PV (rows 0-3)
//     AND the softmax denominator (row 4, via the ones-row) on the MFMA
//     pipe -- which runs CONCURRENTLY with the VALU/trans complex (m114),
//     removing the 10 v_pk_fma/j PV load from the saturated issue port.
//   - epilogue is per-wave (no split-K merge at all): C/D layout (verified
//     m89): col = lane&15 = q, row = 4*(lane>>4)+reg. Group-0 lanes hold the
//     4 dims, group-1 reg0 holds den; 2 shuffles + project + store.
// ---------------------------------------------------------------------------
__global__ __launch_bounds__(512, 4) void attn_fused_kernel(
    const float* __restrict__ x, const float* __restrict__ theta,
    const float* __restrict__ Wout, float* __restrict__ outp) {
  __shared__ __align__(16) f16 lds[LDS_HALVES];

  const int b = blockIdx.y;
  const int t = threadIdx.x;
  const int w = t >> 6;
  const int lane = t & 63;
  const int g = lane >> 4;  // 16-lane group = k-slot group
  const int n = lane & 15;  // q-column within the wave's q-tile

  float th[8];
#pragma unroll
  for (int e = 0; e < 8; ++e) th[e] = theta[e];

  // ---- stage chunk 0 (k rows 0..1023): main f16 rows + transposed copy ----
#pragma unroll
  for (int i = 0; i < 2; ++i) {
    const int l = t + 512 * i;
    const float4* xr = (const float4*)(x + ((size_t)b * NS + l) * 8);
    float4 lo = xr[0], hi = xr[1];
    h8 hv;
    hv[0] = (f16)__cosf(lo.x + th[0]);
    hv[1] = (f16)__cosf(lo.y + th[1]);
    hv[2] = (f16)__cosf(lo.z + th[2]);
    hv[3] = (f16)__cosf(lo.w + th[3]);
    hv[4] = (f16)__cosf(hi.x + th[4]);
    hv[5] = (f16)__cosf(hi.y + th[5]);
    hv[6] = (f16)__cosf(hi.z + th[6]);
    hv[7] = (f16)__cosf(hi.w + th[7]);
    ((h8*)lds)[l] = hv;
#pragma unroll
    for (int e = 0; e < 8; ++e) lds[TR_BASE + e * TR_STRIDE + l] = hv[e];
    lds[TR_BASE + 8 * TR_STRIDE + l] = (f16)1.0f;  // ones row (denominator)
    lds[TR_BASE + 9 * TR_STRIDE + l] = (f16)0.0f;  // zeros row (A rows 5..15)
  }

  // ---- prefetch chunk 1 raw x into registers ----
  float4 pf[2][2];
#pragma unroll
  for (int i = 0; i < 2; ++i) {
    const int l = t + 512 * i;
    const float4* xr = (const float4*)(x + ((size_t)b * NS + 1024 + l) * 8);
    pf[i][0] = xr[0];
    pf[i][1] = xr[1];
  }

  // ---- this lane's q column (pre-scaled), as f16 pairs for v_dot2 ----
  h2 qh[4];
  {
    const float4* xq = (const float4*)(
        x + ((size_t)b * NS + blockIdx.x * 128 + w * 16 + n) * 8);
    float4 lo = xq[0], hi = xq[1];
    qh[0] = (h2){(f16)(__cosf(lo.x + th[0]) * QS), (f16)(__cosf(lo.y + th[1]) * QS)};
    qh[1] = (h2){(f16)(__cosf(lo.z + th[2]) * QS), (f16)(__cosf(lo.w + th[3]) * QS)};
    qh[2] = (h2){(f16)(__cosf(hi.x + th[4]) * QS), (f16)(__cosf(hi.y + th[5]) * QS)};
    qh[3] = (h2){(f16)(__cosf(hi.z + th[6]) * QS), (f16)(__cosf(hi.w + th[7]) * QS)};
  }

  // per-lane constant k-slot offsets within a 32-row step (see header comment)
  int offr[4];
#pragma unroll
  for (int r = 0; r < 4; ++r) offr[r] = 8 * ((r + g) & 3) + 2 * g;
  // A-fragment source row in the transposed copy, per head:
  //   m<4 -> dim (head*4+m); m==4 -> ones; m>4 -> zeros
  const int d0 = (n < 4) ? n : ((n == 4) ? 8 : 9);
  const int d1 = (n < 4) ? (n + 4) : d0;
  const f16* trp0 = lds + TR_BASE + d0 * TR_STRIDE;
  const f16* trp1 = lds + TR_BASE + d1 * TR_STRIDE;

  f32x4 C0 = {0.f, 0.f, 0.f, 0.f};  // head0: rows 0-3 = dims, row4 = den
  f32x4 C1 = {0.f, 0.f, 0.f, 0.f};  // head1

  __syncthreads();  // chunk 0 staged

  for (int chunk = 0; chunk < 2; ++chunk) {
    if (chunk == 1) {
      __syncthreads();  // chunk 0 fully consumed
      // restage chunk 1 from prefetched registers (no memory latency)
#pragma unroll
      for (int i = 0; i < 2; ++i) {
        const int l = t + 512 * i;
        float4 lo = pf[i][0], hi = pf[i][1];
        h8 hv;
        hv[0] = (f16)__cosf(lo.x + th[0]);
        hv[1] = (f16)__cosf(lo.y + th[1]);
        hv[2] = (f16)__cosf(lo.z + th[2]);
        hv[3] = (f16)__cosf(lo.w + th[3]);
        hv[4] = (f16)__cosf(hi.x + th[4]);
        hv[5] = (f16)__cosf(hi.y + th[5]);
        hv[6] = (f16)__cosf(hi.z + th[6]);
        hv[7] = (f16)__cosf(hi.w + th[7]);
        ((h8*)lds)[l] = hv;
#pragma unroll
        for (int e = 0; e < 8; ++e) lds[TR_BASE + e * TR_STRIDE + l] = hv[e];
      }
      __syncthreads();  // chunk 1 staged
    }

#pragma unroll 2
    for (int step = 0; step < 32; ++step) {
      const int kb = step * 32;
      float P0[8], P1[8];
      // scores for this lane's 8 k-slots (both heads), straight into B layout
#pragma unroll
      for (int r = 0; r < 4; ++r) {
#pragma unroll
        for (int p = 0; p < 2; ++p) {
          h8 row = ((const h8*)lds)[kb + offr[r] + p];
          h2 r01 = (h2){row[0], row[1]};
          h2 r23 = (h2){row[2], row[3]};
          h2 r45 = (h2){row[4], row[5]};
          h2 r67 = (h2){row[6], row[7]};
          const int s = 2 * r + p;
          P0[s] = __builtin_amdgcn_fdot2(
              qh[0], r01, __builtin_amdgcn_fdot2(qh[1], r23, 0.f, false),
              false);
          P1[s] = __builtin_amdgcn_fdot2(
              qh[2], r45, __builtin_amdgcn_fdot2(qh[3], r67, 0.f, false),
              false);
        }
      }
#pragma unroll
      for (int s = 0; s < 8; ++s) {
        P0[s] = __builtin_amdgcn_exp2f(P0[s]);
        P1[s] = __builtin_amdgcn_exp2f(P1[s]);
      }
      // pack B fragments (f16) and load A fragments (h^T + ones/zeros rows)
      h8 B0, B1, A0, A1;
#pragma unroll
      for (int r = 0; r < 4; ++r) {
        h2 b0 = cvt_pk_f16(P0[2 * r], P0[2 * r + 1]);
        h2 b1 = cvt_pk_f16(P1[2 * r], P1[2 * r + 1]);
        B0[2 * r] = b0[0];
        B0[2 * r + 1] = b0[1];
        B1[2 * r] = b1[0];
        B1[2 * r + 1] = b1[1];
        h2 a0 = *(const h2*)&trp0[kb + offr[r]];
        h2 a1 = *(const h2*)&trp1[kb + offr[r]];
        A0[2 * r] = a0[0];
        A0[2 * r + 1] = a0[1];
        A1[2 * r] = a1[0];
        A1[2 * r + 1] = a1[1];
      }
      C0 = __builtin_amdgcn_mfma_f32_16x16x32_f16(A0, B0, C0, 0, 0, 0);
      C1 = __builtin_amdgcn_mfma_f32_16x16x32_f16(A1, B1, C1, 0, 0, 0);
    }
  }

  // ---- per-wave epilogue: C cols = q (lane&15), rows = 4*(lane>>4)+reg ----
  const float den0 = __shfl(C0[0], 16 + n, 64);  // row 4 = ones-row sum
  const float den1 = __shfl(C1[0], 16 + n, 64);
  if (lane < 16) {  // group 0 holds rows 0-3 = numerator dims
    const float i0 = 1.0f / den0, i1 = 1.0f / den1;
    float m8[8] = {C0[0] * i0, C0[1] * i0, C0[2] * i0, C0[3] * i0,
                   C1[0] * i1, C1[1] * i1, C1[2] * i1, C1[3] * i1};
    float o[8];
#pragma unroll
    for (int e = 0; e < 8; ++e) {
      float s = 0.f;
#pragma unroll
      for (int f = 0; f < 8; ++f) s += m8[f] * Wout[e * 8 + f];
      o[e] = s;
    }
    const int q = blockIdx.x * 128 + w * 16 + n;
    float4* op = (float4*)(outp + ((size_t)b * NS + q) * 8);
    op[0] = make_float4(o[0], o[1], o[2], o[3]);
    op[1] = make_float4(o[4], o[5], o[6], o[7]);
  }
}

extern "C" void kernel_launch(void* const* d_in, const int* in_sizes, int n_in,
                              void* d_out, int out_size, void* d_ws,
                              size_t ws_size, hipStream_t stream) {
  const float* x = (const float*)d_in[0];      // [32, 2048, 8]
  const float* theta = (const float*)d_in[1];  // [8]
  const float* W = (const float*)d_in[2];      // [8, 8]
  float* out = (float*)d_out;                  // [32, 2048, 8]
  (void)d_ws;
  (void)ws_size;

  // 512 blocks (16 q-supertiles x 32 batches) of 8 waves; ~37 KB LDS each
  // -> 2 blocks/CU, 16 waves/CU = 4 waves/SIMD.
  attn_fused_kernel<<<dim3(NS / 128, NB), 512, 0, stream>>>(x, theta, W, out);
}

// Round 5
// 92.706 us; speedup vs baseline: 1.4786x; 1.2109x over previous
//
#include <hip/hip_runtime.h>

#define NB 32
#define NS 2048
// (1/sqrt(d_k)) * log2(e) folded into q so scores feed v_exp_f32 (2^x) directly
#define QS 0.72134752044448170367f

typedef _Float16 f16;
typedef _Float16 h2 __attribute__((ext_vector_type(2)));
typedef _Float16 h4 __attribute__((ext_vector_type(4)));
typedef _Float16 h8 __attribute__((ext_vector_type(8)));
typedef float f32x4 __attribute__((ext_vector_type(4)));

__device__ __forceinline__ h2 cvt_pk_f16(float a, float b) {
  return __builtin_bit_cast(h2, __builtin_amdgcn_cvt_pkrtz(a, b));
}

// LDS geometry (units: halves/f16):
//   main      : [1024][8]  f16 k-rows (16 B/row)            -> 8192 halves
//   transposed: [10][1032] f16, row d = dim (0-7), 8 = ones, 9 = zeros
//               stride 1032 halves (2064 B) to spread banks  -> 10320 halves
#define TR_STRIDE 1032
#define TR_BASE 8192
#define LDS_HALVES (8192 + 10 * 1032)
#define ZIDX (TR_BASE + 9 * TR_STRIDE)  // zeros row (also zero A-frag source)

// ---------------------------------------------------------------------------
// All-MFMA fused attention (R5: QK^T moved onto the matrix pipe too).
//   - block = 512 thr = 8 waves; block owns 128 q (wave w owns a 16-q tile).
//   - wave walks all 2048 k in 64 steps of 32 (2 LDS chunks of 1024 rows).
//   - SCORES via MFMA: per (head, 16-k-half) one mfma_f32_16x16x32_f16 with
//     A slots (g=0, j<4) = K[kb+16h+m][d], B slots (g=0, j<4) = Q[n][d]*QS
//     (loop-invariant, in regs), all other slots ZERO on both sides (g>0
//     lanes read the LDS zeros-row). Correct for ANY HW slot map as long as
//     kappa_A == kappa_B -- proven by R4 passing with random data.
//   - D layout (m89): col = lane&15 = q, row = 4g+reg. So each lane holds
//     P[k = kb+16h+4g+r][q=n] after exp -- used DIRECTLY as the PV
//     B-fragment by DEFINING its (g,j)->k map as 16*(j>>2)+4g+(j&3) and
//     building the PV A-fragment (h^T rows from the transposed LDS copy)
//     with the SAME formula (2 contiguous ds_read_b64 per head). The true
//     slot permutation cancels. No shuffles, no LDS round-trip for P.
//   - PV A rows: m<4 -> dim (head*4+m); m==4 -> ones (denominator); else 0.
//   - epilogue per-wave (R4): group-0 lanes hold numerator dims, row 4 = den.
//   - R1-R4 machine model: issue complex (VALU+trans) is the constraint;
//     v_pk 4cyc, v_exp 8cyc. This round deletes 32 fdot2 + 8 b128 reads/step
//     (-~95 cyc/step of issue), leaving exp (128 cyc/step) dominant.
// ---------------------------------------------------------------------------
__global__ __launch_bounds__(512, 4) void attn_fused_kernel(
    const float* __restrict__ x, const float* __restrict__ theta,
    const float* __restrict__ Wout, float* __restrict__ outp) {
  __shared__ __align__(16) f16 lds[LDS_HALVES];

  const int b = blockIdx.y;
  const int t = threadIdx.x;
  const int w = t >> 6;
  const int lane = t & 63;
  const int g = lane >> 4;  // 16-lane group
  const int n = lane & 15;  // q-column within the wave's q-tile

  float th[8];
#pragma unroll
  for (int e = 0; e < 8; ++e) th[e] = theta[e];

  // ---- stage chunk 0 (k rows 0..1023): main f16 rows + transposed copy ----
#pragma unroll
  for (int i = 0; i < 2; ++i) {
    const int l = t + 512 * i;
    const float4* xr = (const float4*)(x + ((size_t)b * NS + l) * 8);
    float4 lo = xr[0], hi = xr[1];
    h8 hv;
    hv[0] = (f16)__cosf(lo.x + th[0]);
    hv[1] = (f16)__cosf(lo.y + th[1]);
    hv[2] = (f16)__cosf(lo.z + th[2]);
    hv[3] = (f16)__cosf(lo.w + th[3]);
    hv[4] = (f16)__cosf(hi.x + th[4]);
    hv[5] = (f16)__cosf(hi.y + th[5]);
    hv[6] = (f16)__cosf(hi.z + th[6]);
    hv[7] = (f16)__cosf(hi.w + th[7]);
    ((h8*)lds)[l] = hv;
#pragma unroll
    for (int e = 0; e < 8; ++e) lds[TR_BASE + e * TR_STRIDE + l] = hv[e];
    lds[TR_BASE + 8 * TR_STRIDE + l] = (f16)1.0f;  // ones row (denominator)
    lds[ZIDX + l] = (f16)0.0f;                     // zeros row
  }

  // ---- prefetch chunk 1 raw x into registers ----
  float4 pf[2][2];
#pragma unroll
  for (int i = 0; i < 2; ++i) {
    const int l = t + 512 * i;
    const float4* xr = (const float4*)(x + ((size_t)b * NS + 1024 + l) * 8);
    pf[i][0] = xr[0];
    pf[i][1] = xr[1];
  }

  // ---- loop-invariant score B-fragments: Q[n][d]*QS at (g=0, j<4) ----
  h8 Bq0, Bq1;
#pragma unroll
  for (int j = 0; j < 8; ++j) {
    Bq0[j] = (f16)0.f;
    Bq1[j] = (f16)0.f;
  }
  if (g == 0) {
    const float4* xq = (const float4*)(
        x + ((size_t)b * NS + blockIdx.x * 128 + w * 16 + n) * 8);
    float4 lo = xq[0], hi = xq[1];
    Bq0[0] = (f16)(__cosf(lo.x + th[0]) * QS);
    Bq0[1] = (f16)(__cosf(lo.y + th[1]) * QS);
    Bq0[2] = (f16)(__cosf(lo.z + th[2]) * QS);
    Bq0[3] = (f16)(__cosf(lo.w + th[3]) * QS);
    Bq1[0] = (f16)(__cosf(hi.x + th[4]) * QS);
    Bq1[1] = (f16)(__cosf(hi.y + th[5]) * QS);
    Bq1[2] = (f16)(__cosf(hi.z + th[6]) * QS);
    Bq1[3] = (f16)(__cosf(hi.w + th[7]) * QS);
  }

  // score A-frag source: g==0 reads main k-rows (advance 256 halves/step),
  // g>0 reads the zeros row at a constant address (broadcast).
  const int sini = (g == 0) ? n * 8 : ZIDX;
  const int sadv = (g == 0) ? 256 : 0;

  // PV A-frag source rows in the transposed copy, per head:
  const int d0 = (n < 4) ? n : ((n == 4) ? 8 : 9);
  const int d1 = (n < 4) ? (n + 4) : d0;
  const int t0ini = TR_BASE + d0 * TR_STRIDE + 4 * g;
  const int t1ini = TR_BASE + d1 * TR_STRIDE + 4 * g;

  const f32x4 Z = {0.f, 0.f, 0.f, 0.f};
  f32x4 C0 = Z;  // head0: rows 0-3 = dims, row 4 = den (col = q)
  f32x4 C1 = Z;  // head1

  __syncthreads();  // chunk 0 staged

  for (int chunk = 0; chunk < 2; ++chunk) {
    if (chunk == 1) {
      __syncthreads();  // chunk 0 fully consumed
#pragma unroll
      for (int i = 0; i < 2; ++i) {
        const int l = t + 512 * i;
        float4 lo = pf[i][0], hi = pf[i][1];
        h8 hv;
        hv[0] = (f16)__cosf(lo.x + th[0]);
        hv[1] = (f16)__cosf(lo.y + th[1]);
        hv[2] = (f16)__cosf(lo.z + th[2]);
        hv[3] = (f16)__cosf(lo.w + th[3]);
        hv[4] = (f16)__cosf(hi.x + th[4]);
        hv[5] = (f16)__cosf(hi.y + th[5]);
        hv[6] = (f16)__cosf(hi.z + th[6]);
        hv[7] = (f16)__cosf(hi.w + th[7]);
        ((h8*)lds)[l] = hv;
#pragma unroll
        for (int e = 0; e < 8; ++e) lds[TR_BASE + e * TR_STRIDE + l] = hv[e];
      }
      __syncthreads();  // chunk 1 staged
    }

    int sc = sini;
    int tc0 = t0ini;
    int tc1 = t1ini;
#pragma unroll 2
    for (int step = 0; step < 32; ++step) {
      // ---- score A-fragments (K rows via group-0 lanes; zeros elsewhere)
      h4 k00 = *(const h4*)(lds + sc);        // rows kb+n,    head0 dims
      h4 k10 = *(const h4*)(lds + sc + 4);    //               head1 dims
      h4 k01 = *(const h4*)(lds + sc + 128);  // rows kb+16+n, head0 dims
      h4 k11 = *(const h4*)(lds + sc + 132);  //               head1 dims
      // ---- PV A-fragments (h^T + ones/zeros rows), same (g,j)->k formula
      //      as the score-D-derived B-fragment: k = 16*(j>>2)+4g+(j&3)
      h4 a00 = *(const h4*)(lds + tc0);       // head0, cols kb+4g..+3
      h4 a01 = *(const h4*)(lds + tc0 + 16);  //        cols kb+16+4g..+3
      h4 a10 = *(const h4*)(lds + tc1);       // head1
      h4 a11 = *(const h4*)(lds + tc1 + 16);

      h8 A00, A01, A10, A11, V0, V1;
#pragma unroll
      for (int j = 0; j < 4; ++j) {
        A00[j] = k00[j];
        A01[j] = k01[j];
        A10[j] = k10[j];
        A11[j] = k11[j];
        A00[j + 4] = (f16)0.f;
        A01[j + 4] = (f16)0.f;
        A10[j + 4] = (f16)0.f;
        A11[j + 4] = (f16)0.f;
        V0[j] = a00[j];
        V0[j + 4] = a01[j];
        V1[j] = a10[j];
        V1[j + 4] = a11[j];
      }

      // ---- scores on the MFMA pipe: D rows = k (4g+reg), cols = q ----
      f32x4 S00 = __builtin_amdgcn_mfma_f32_16x16x32_f16(A00, Bq0, Z, 0, 0, 0);
      f32x4 S01 = __builtin_amdgcn_mfma_f32_16x16x32_f16(A01, Bq0, Z, 0, 0, 0);
      f32x4 S10 = __builtin_amdgcn_mfma_f32_16x16x32_f16(A10, Bq1, Z, 0, 0, 0);
      f32x4 S11 = __builtin_amdgcn_mfma_f32_16x16x32_f16(A11, Bq1, Z, 0, 0, 0);

      // ---- exp (trans pipe) + pack into the PV B-fragment ----
      h8 B0, B1;
      h2 p;
      p = cvt_pk_f16(__builtin_amdgcn_exp2f(S00[0]),
                     __builtin_amdgcn_exp2f(S00[1]));
      B0[0] = p[0];
      B0[1] = p[1];
      p = cvt_pk_f16(__builtin_amdgcn_exp2f(S00[2]),
                     __builtin_amdgcn_exp2f(S00[3]));
      B0[2] = p[0];
      B0[3] = p[1];
      p = cvt_pk_f16(__builtin_amdgcn_exp2f(S01[0]),
                     __builtin_amdgcn_exp2f(S01[1]));
      B0[4] = p[0];
      B0[5] = p[1];
      p = cvt_pk_f16(__builtin_amdgcn_exp2f(S01[2]),
                     __builtin_amdgcn_exp2f(S01[3]));
      B0[6] = p[0];
      B0[7] = p[1];
      p = cvt_pk_f16(__builtin_amdgcn_exp2f(S10[0]),
                     __builtin_amdgcn_exp2f(S10[1]));
      B1[0] = p[0];
      B1[1] = p[1];
      p = cvt_pk_f16(__builtin_amdgcn_exp2f(S10[2]),
                     __builtin_amdgcn_exp2f(S10[3]));
      B1[2] = p[0];
      B1[3] = p[1];
      p = cvt_pk_f16(__builtin_amdgcn_exp2f(S11[0]),
                     __builtin_amdgcn_exp2f(S11[1]));
      B1[4] = p[0];
      B1[5] = p[1];
      p = cvt_pk_f16(__builtin_amdgcn_exp2f(S11[2]),
                     __builtin_amdgcn_exp2f(S11[3]));
      B1[6] = p[0];
      B1[7] = p[1];

      // ---- PV (+denominator via ones-row) on the MFMA pipe ----
      C0 = __builtin_amdgcn_mfma_f32_16x16x32_f16(V0, B0, C0, 0, 0, 0);
      C1 = __builtin_amdgcn_mfma_f32_16x16x32_f16(V1, B1, C1, 0, 0, 0);

      sc += sadv;
      tc0 += 32;
      tc1 += 32;
    }
  }

  // ---- per-wave epilogue: C cols = q (lane&15), rows = 4*(lane>>4)+reg ----
  const float den0 = __shfl(C0[0], 16 + n, 64);  // row 4 = ones-row sum
  const float den1 = __shfl(C1[0], 16 + n, 64);
  if (lane < 16) {  // group 0 holds rows 0-3 = numerator dims
    const float i0 = 1.0f / den0, i1 = 1.0f / den1;
    float m8[8] = {C0[0] * i0, C0[1] * i0, C0[2] * i0, C0[3] * i0,
                   C1[0] * i1, C1[1] * i1, C1[2] * i1, C1[3] * i1};
    float o[8];
#pragma unroll
    for (int e = 0; e < 8; ++e) {
      float s = 0.f;
#pragma unroll
      for (int f = 0; f < 8; ++f) s += m8[f] * Wout[e * 8 + f];
      o[e] = s;
    }
    const int q = blockIdx.x * 128 + w * 16 + n;
    float4* op = (float4*)(outp + ((size_t)b * NS + q) * 8);
    op[0] = make_float4(o[0], o[1], o[2], o[3]);
    op[1] = make_float4(o[4], o[5], o[6], o[7]);
  }
}

extern "C" void kernel_launch(void* const* d_in, const int* in_sizes, int n_in,
                              void* d_out, int out_size, void* d_ws,
                              size_t ws_size, hipStream_t stream) {
  const float* x = (const float*)d_in[0];      // [32, 2048, 8]
  const float* theta = (const float*)d_in[1];  // [8]
  const float* W = (const float*)d_in[2];      // [8, 8]
  float* out = (float*)d_out;                  // [32, 2048, 8]
  (void)d_ws;
  (void)ws_size;

  // 512 blocks (16 q-supertiles x 32 batches) of 8 waves; ~37 KB LDS each
  // -> 2 blocks/CU, 16 waves/CU = 4 waves/SIMD.
  attn_fused_kernel<<<dim3(NS / 128, NB), 512, 0, stream>>>(x, theta, W, out);
}